// Round 1
// baseline (170.371 us; speedup 1.0000x reference)
//
#include <hip/hip_runtime.h>
#include <stdint.h>

// Problem constants (B=2048, N=16, T=1024)
#define T_STEPS 1024
#define NWORDS  256          // u64 mask words per batch (4 timesteps packed per word)
#define NB      8            // batches per scan block
#define SCAN_BLOCK (NB * 16) // 128 threads: 8 batches x 16 output neurons

// ---------------------------------------------------------------------------
// Kernel 1: compress binary spike floats -> 16-bit masks, 4 timesteps per u64.
// Grid: B blocks x 256 threads. Fully coalesced float4 reads (16B/lane).
// ---------------------------------------------------------------------------
__global__ __launch_bounds__(256) void k_maskify(const float* __restrict__ spike,
                                                 unsigned long long* __restrict__ masks) {
    const int b  = blockIdx.x;
    const int tc = threadIdx.x;  // handles t = 4*tc .. 4*tc+3
    const float4* sp = reinterpret_cast<const float4*>(spike) + (size_t)b * (16 * NWORDS);
    unsigned int m0 = 0, m1 = 0, m2 = 0, m3 = 0;
#pragma unroll
    for (int i = 0; i < 16; ++i) {
        float4 v = sp[i * NWORDS + tc];
        m0 |= (v.x >= 0.5f) ? (1u << i) : 0u;
        m1 |= (v.y >= 0.5f) ? (1u << i) : 0u;
        m2 |= (v.z >= 0.5f) ? (1u << i) : 0u;
        m3 |= (v.w >= 0.5f) ? (1u << i) : 0u;
    }
    masks[(size_t)b * NWORDS + tc] =
        (unsigned long long)m0 | ((unsigned long long)m1 << 16) |
        ((unsigned long long)m2 << 32) | ((unsigned long long)m3 << 48);
}

// ---------------------------------------------------------------------------
// Kernel 2: CUBA LIF scan. One thread per (batch, out-neuron) chain, fp64
// internal state (must match the float64 numpy reference with ZERO spike
// flips: one flip = 3.5e4 error > 2.74e4 threshold).
// z[o] from 4x 4-bit nibble tables in LDS. Spike count via __ballot +
// popcount over the 16-lane batch group; 17-entry output table.
// ---------------------------------------------------------------------------
__global__ __launch_bounds__(SCAN_BLOCK) void k_scan(const float* __restrict__ W,
                                                     const unsigned long long* __restrict__ masks,
                                                     const float* __restrict__ spike,
                                                     float* __restrict__ out) {
    __shared__ double ztab[4][16][16];            // [seg][nibble][o]  (8 KiB)
    __shared__ unsigned long long mlds[NB][NWORDS]; // 16 KiB
    __shared__ float outtab[17];

    const int tid = threadIdx.x;
    const int bb  = tid >> 4;   // local batch 0..NB-1
    const int o   = tid & 15;   // output neuron

    // Build z nibble tables: ztab[seg][idx][o] = sum_{j: idx bit j} W[o][seg*4+j]
    for (int e = tid; e < 4 * 16 * 16; e += SCAN_BLOCK) {
        const int oo  = e & 15;
        const int idx = (e >> 4) & 15;
        const int seg = e >> 8;
        double s = 0.0;
#pragma unroll
        for (int j = 0; j < 4; ++j)
            if (idx & (1 << j)) s += (double)W[oo * 16 + seg * 4 + j];
        ztab[seg][idx][oo] = s;
    }
    // out[k] = exp((16-k)*ln2 + k*log(2*cosh(1)))  = 2^16 * cosh(1)^k
    if (tid < 17) {
        const double ln2  = 0.69314718055994530941723212145818;
        const double l2c1 = log(2.0 * cosh(1.0));
        outtab[tid] = (float)exp((16.0 - (double)tid) * ln2 + (double)tid * l2c1);
    }

    if (masks != nullptr) {
        // Fast path: masks precomputed by k_maskify (coalesced copy to LDS).
        const unsigned long long* src = masks + (size_t)blockIdx.x * NB * NWORDS;
        for (int e = tid; e < NB * NWORDS; e += SCAN_BLOCK)
            ((unsigned long long*)mlds)[e] = src[e];
    } else {
        // Fallback (ws too small): build masks from raw spikes in-kernel.
        const int part = tid & 15;
        const float4* spb = reinterpret_cast<const float4*>(spike) +
                            (size_t)(blockIdx.x * NB + bb) * (16 * NWORDS);
        for (int w = 0; w < 16; ++w) {
            const int tc = part * 16 + w;
            unsigned int m0 = 0, m1 = 0, m2 = 0, m3 = 0;
#pragma unroll
            for (int i = 0; i < 16; ++i) {
                float4 v = spb[i * NWORDS + tc];
                m0 |= (v.x >= 0.5f) ? (1u << i) : 0u;
                m1 |= (v.y >= 0.5f) ? (1u << i) : 0u;
                m2 |= (v.z >= 0.5f) ? (1u << i) : 0u;
                m3 |= (v.w >= 0.5f) ? (1u << i) : 0u;
            }
            mlds[bb][tc] = (unsigned long long)m0 | ((unsigned long long)m1 << 16) |
                           ((unsigned long long)m2 << 32) | ((unsigned long long)m3 << 48);
        }
    }
    __syncthreads();

    double c = 0.0, v = 0.0;
    const int b = blockIdx.x * NB + bb;
    float* outp = out + (size_t)b * T_STEPS;
    const unsigned long long* mrow = &mlds[bb][0];
    const int grp_sh = tid & 48;     // (lane/16)*16 : this batch-group's ballot slot
    const bool writer = (o == 0);

    for (int tg = 0; tg < NWORDS; ++tg) {
        const unsigned long long mw = mrow[tg];  // LDS broadcast within group
#pragma unroll
        for (int j = 0; j < 4; ++j) {
            const unsigned int m = (unsigned int)(mw >> (16 * j)) & 0xFFFFu;
            const double z = (ztab[0][m & 15][o] + ztab[1][(m >> 4) & 15][o]) +
                             (ztab[2][(m >> 8) & 15][o] + ztab[3][(m >> 12) & 15][o]);
            c = fma(c, 0.75, z);                 // c = 0.75*c + z
            v = fma(v, 0.97, c);                 // v = 0.97*v + c
            const bool s = (v >= 1.25);
            const unsigned long long bal = __ballot(s);
            v = s ? 0.0 : v;                     // hard reset
            if (writer) {
                const int k = (int)__popcll((bal >> grp_sh) & 0xFFFFull);
                outp[tg * 4 + j] = outtab[k];
            }
        }
    }
}

extern "C" void kernel_launch(void* const* d_in, const int* in_sizes, int n_in,
                              void* d_out, int out_size, void* d_ws, size_t ws_size,
                              hipStream_t stream) {
    const float* spike = (const float*)d_in[0];
    const float* W     = (const float*)d_in[1];
    float* out         = (float*)d_out;

    const int B = in_sizes[0] / (16 * T_STEPS);  // 2048

    const size_t mask_bytes = (size_t)B * NWORDS * sizeof(unsigned long long);  // 4 MiB
    unsigned long long* masks = nullptr;
    if (ws_size >= mask_bytes) {
        masks = (unsigned long long*)d_ws;
        k_maskify<<<B, 256, 0, stream>>>(spike, masks);
    }
    k_scan<<<B / NB, SCAN_BLOCK, 0, stream>>>(W, masks, spike, out);
}

// Round 3
// 116.299 us; speedup vs baseline: 1.4649x; 1.4649x over previous
//
#include <hip/hip_runtime.h>
#include <stdint.h>

// Problem constants (B=2048, N=16, T=1024)
#define T_STEPS 1024
#define NWORDS  256          // u64 mask words per batch (4 timesteps packed per word)
#define NB      8            // batches per scan block
#define SCAN_BLOCK (NB * 16) // 128 threads: 8 batches x 16 output neurons

// ---------------------------------------------------------------------------
// Kernel 1: compress binary spike floats -> 16-bit masks, 4 timesteps per u64.
// Grid: B blocks x 256 threads. Fully coalesced float4 reads (16B/lane).
// This pass owns the HBM-bound 128 MiB read (~20 us floor at 6.3 TB/s).
// ---------------------------------------------------------------------------
__global__ __launch_bounds__(256) void k_maskify(const float* __restrict__ spike,
                                                 unsigned long long* __restrict__ masks) {
    const int b  = blockIdx.x;
    const int tc = threadIdx.x;  // handles t = 4*tc .. 4*tc+3
    const float4* sp = reinterpret_cast<const float4*>(spike) + (size_t)b * (16 * NWORDS);
    unsigned int m0 = 0, m1 = 0, m2 = 0, m3 = 0;
#pragma unroll
    for (int i = 0; i < 16; ++i) {
        float4 v = sp[i * NWORDS + tc];
        m0 |= (v.x >= 0.5f) ? (1u << i) : 0u;
        m1 |= (v.y >= 0.5f) ? (1u << i) : 0u;
        m2 |= (v.z >= 0.5f) ? (1u << i) : 0u;
        m3 |= (v.w >= 0.5f) ? (1u << i) : 0u;
    }
    masks[(size_t)b * NWORDS + tc] =
        (unsigned long long)m0 | ((unsigned long long)m1 << 16) |
        ((unsigned long long)m2 << 32) | ((unsigned long long)m3 << 48);
}

// ---------------------------------------------------------------------------
// Kernel 2: CUBA LIF scan, fp64 state (bit-exact vs float64 numpy ref in R1;
// keep summation order / fma forms IDENTICAL). One thread per (batch,o) chain.
//
// R2 change: software-pipelined z prefetch. z values depend only on the spike
// masks, not on (c,v) state, so the 16 ztab LDS reads for word tg+1 are issued
// while computing word tg, and mask words are read two ahead. This takes the
// ~120-cyc ds_read latency (which was ~330 of the measured ~350 cyc/step) off
// the serial critical path, leaving only the f64 fma/cmp/select chain.
// All prefetch buffers use compile-time indices only (no scratch).
// ---------------------------------------------------------------------------
__global__ __launch_bounds__(SCAN_BLOCK) void k_scan(const float* __restrict__ W,
                                                     const unsigned long long* __restrict__ masks,
                                                     const float* __restrict__ spike,
                                                     float* __restrict__ out) {
    __shared__ double ztab[4][16][16];              // [seg][nibble][o]  (8 KiB)
    __shared__ unsigned long long mlds[NB][NWORDS]; // 16 KiB
    __shared__ float outtab[17];

    const int tid = threadIdx.x;
    const int bb  = tid >> 4;   // local batch 0..NB-1
    const int o   = tid & 15;   // output neuron

    // Build z nibble tables: ztab[seg][idx][o] = sum_{j: idx bit j} W[o][seg*4+j]
    for (int e = tid; e < 4 * 16 * 16; e += SCAN_BLOCK) {
        const int oo  = e & 15;
        const int idx = (e >> 4) & 15;
        const int seg = e >> 8;
        double s = 0.0;
#pragma unroll
        for (int j = 0; j < 4; ++j)
            if (idx & (1 << j)) s += (double)W[oo * 16 + seg * 4 + j];
        ztab[seg][idx][oo] = s;
    }
    // out[k] = exp((16-k)*ln2 + k*log(2*cosh(1)))  = 2^16 * cosh(1)^k
    if (tid < 17) {
        const double ln2  = 0.69314718055994530941723212145818;
        const double l2c1 = log(2.0 * cosh(1.0));
        outtab[tid] = (float)exp((16.0 - (double)tid) * ln2 + (double)tid * l2c1);
    }

    if (masks != nullptr) {
        // Fast path: masks precomputed by k_maskify (coalesced copy to LDS).
        const unsigned long long* src = masks + (size_t)blockIdx.x * NB * NWORDS;
        for (int e = tid; e < NB * NWORDS; e += SCAN_BLOCK)
            ((unsigned long long*)mlds)[e] = src[e];
    } else {
        // Fallback (ws too small): build masks from raw spikes in-kernel.
        const int part = tid & 15;
        const float4* spb = reinterpret_cast<const float4*>(spike) +
                            (size_t)(blockIdx.x * NB + bb) * (16 * NWORDS);
        for (int w = 0; w < 16; ++w) {
            const int tc = part * 16 + w;
            unsigned int m0 = 0, m1 = 0, m2 = 0, m3 = 0;
#pragma unroll
            for (int i = 0; i < 16; ++i) {
                float4 v = spb[i * NWORDS + tc];
                m0 |= (v.x >= 0.5f) ? (1u << i) : 0u;
                m1 |= (v.y >= 0.5f) ? (1u << i) : 0u;
                m2 |= (v.z >= 0.5f) ? (1u << i) : 0u;
                m3 |= (v.w >= 0.5f) ? (1u << i) : 0u;
            }
            mlds[bb][tc] = (unsigned long long)m0 | ((unsigned long long)m1 << 16) |
                           ((unsigned long long)m2 << 32) | ((unsigned long long)m3 << 48);
        }
    }
    __syncthreads();

    double c = 0.0, v = 0.0;
    const int b = blockIdx.x * NB + bb;
    float4* outp4 = reinterpret_cast<float4*>(out + (size_t)b * T_STEPS);
    const unsigned long long* mrow = &mlds[bb][0];
    const int grp_sh = tid & 48;     // (lane/16)*16 : this batch-group's ballot slot
    const bool writer = (o == 0);

    // Prefetch the 16 z-table values for one mask word into registers.
    // Static indices only (fully unrolled) -> stays in VGPRs.
#define PREFETCH(Z, MW)                                                         \
    {                                                                           \
        const unsigned long long _mw = (MW);                                    \
        _Pragma("unroll")                                                       \
        for (int j = 0; j < 4; ++j) {                                           \
            const unsigned int m = (unsigned int)(_mw >> (16 * j)) & 0xFFFFu;   \
            Z[4 * j + 0] = ztab[0][m & 15][o];                                  \
            Z[4 * j + 1] = ztab[1][(m >> 4) & 15][o];                           \
            Z[4 * j + 2] = ztab[2][(m >> 8) & 15][o];                           \
            Z[4 * j + 3] = ztab[3][(m >> 12) & 15][o];                          \
        }                                                                       \
    }

    // 4 recurrence steps from prefetched z; one float4 store per word.
    // Numerics identical to R1: same add order, fma(c,0.75,z), fma(v,0.97,c).
#define COMPUTE(Z, TG)                                                          \
    {                                                                           \
        float4 ow;                                                              \
        _Pragma("unroll")                                                       \
        for (int j = 0; j < 4; ++j) {                                           \
            const double z = (Z[4 * j + 0] + Z[4 * j + 1]) +                    \
                             (Z[4 * j + 2] + Z[4 * j + 3]);                     \
            c = fma(c, 0.75, z);                                                \
            v = fma(v, 0.97, c);                                                \
            const bool s = (v >= 1.25);                                         \
            const unsigned long long bal = __ballot(s);                         \
            v = s ? 0.0 : v;                                                    \
            const float oval = outtab[(int)__popcll((bal >> grp_sh) & 0xFFFFull)]; \
            if (j == 0) ow.x = oval; else if (j == 1) ow.y = oval;              \
            else if (j == 2) ow.z = oval; else ow.w = oval;                     \
        }                                                                       \
        if (writer) outp4[TG] = ow;                                             \
    }

    double zA[16], zB[16];
    unsigned long long mw1 = mrow[1];
    PREFETCH(zA, mrow[0]);
    for (int tg = 0; tg < NWORDS - 2; tg += 2) {
        const unsigned long long mw2 = mrow[tg + 2];  // mask two words ahead
        PREFETCH(zB, mw1);                            // z for word tg+1
        COMPUTE(zA, tg);
        const unsigned long long mw3 = mrow[tg + 3];
        PREFETCH(zA, mw2);                            // z for word tg+2
        COMPUTE(zB, tg + 1);
        mw1 = mw3;
    }
    // Epilogue: zA = z(254), mw1 = mask(255)
    PREFETCH(zB, mw1);
    COMPUTE(zA, NWORDS - 2);
    COMPUTE(zB, NWORDS - 1);

#undef PREFETCH
#undef COMPUTE
}

extern "C" void kernel_launch(void* const* d_in, const int* in_sizes, int n_in,
                              void* d_out, int out_size, void* d_ws, size_t ws_size,
                              hipStream_t stream) {
    const float* spike = (const float*)d_in[0];
    const float* W     = (const float*)d_in[1];
    float* out         = (float*)d_out;

    const int B = in_sizes[0] / (16 * T_STEPS);  // 2048

    const size_t mask_bytes = (size_t)B * NWORDS * sizeof(unsigned long long);  // 4 MiB
    unsigned long long* masks = nullptr;
    if (ws_size >= mask_bytes) {
        masks = (unsigned long long*)d_ws;
        k_maskify<<<B, 256, 0, stream>>>(spike, masks);
    }
    k_scan<<<B / NB, SCAN_BLOCK, 0, stream>>>(W, masks, spike, out);
}